// Round 9
// baseline (147.546 us; speedup 1.0000x reference)
//
#include <hip/hip_runtime.h>
#include <hip/hip_bf16.h>

typedef __bf16 bf16x8 __attribute__((ext_vector_type(8)));
typedef float  f32x4  __attribute__((ext_vector_type(4)));

#define DE_   64
#define DV_   64
#define DC_   32
#define DOUT_ 64
#define DIN_  224
#define NFRAG 28   // 7 k-steps * 4 n-tiles
#define TPW   4    // contiguous tiles per wave

// Pre-swizzle W ([224][64] f32 row-major) into bf16 MFMA B-fragment order:
// frag f = ks*4+nt ; lane holds B[k][col] with col = nt*16+(lane&15),
// k = ks*32 + (lane>>4)*8 + j, j=0..7 contiguous -> 16B per lane.
__global__ void prep_w_kernel(const float* __restrict__ W, __bf16* __restrict__ wf) {
    int f    = blockIdx.x;          // 0..27
    int lane = threadIdx.x;         // 0..63
    int ks = f >> 2, nt = f & 3;
    int col = nt * 16 + (lane & 15);
    int k0  = ks * 32 + (lane >> 4) * 8;
    bf16x8 v;
#pragma unroll
    for (int j = 0; j < 8; ++j)
        v[j] = (__bf16)W[(k0 + j) * DOUT_ + col];
    reinterpret_cast<bf16x8*>(wf)[f * 64 + lane] = v;
}

// Convert vdata fp32 -> bf16 (halves gather traffic; gathers then feed MFMA
// A-fragments directly with no per-edge cvt).
__global__ void prep_v_kernel(const float* __restrict__ vdata,
                              __bf16* __restrict__ vb16, int n8) {
    int i = blockIdx.x * blockDim.x + threadIdx.x;
    if (i >= n8) return;
    f32x4 a = reinterpret_cast<const f32x4*>(vdata)[2 * i];
    f32x4 b = reinterpret_cast<const f32x4*>(vdata)[2 * i + 1];
    bf16x8 v;
    v[0] = (__bf16)a[0]; v[1] = (__bf16)a[1]; v[2] = (__bf16)a[2]; v[3] = (__bf16)a[3];
    v[4] = (__bf16)b[0]; v[5] = (__bf16)b[1]; v[6] = (__bf16)b[2]; v[7] = (__bf16)b[3];
    reinterpret_cast<bf16x8*>(vb16)[i] = v;
}

// Each wave handles TPW CONTIGUOUS 16-edge tiles (64 consecutive edges), so
// the live edata/out window stays compact (unlike R6's strided persistence)
// while W is staged into LDS once per block (87 -> 22 MB fabric traffic).
// Ids prefetched one tile ahead to hide the id -> gather chain.
__global__ __launch_bounds__(1024, 2)
void edge_mlp_kernel(const float* __restrict__ edata,
                     const __bf16* __restrict__ vb16,
                     const float* __restrict__ cdata,
                     const int*   __restrict__ snd,
                     const int*   __restrict__ rcv,
                     const __bf16* __restrict__ wf,
                     const float* __restrict__ bias,
                     float* __restrict__ out,
                     int NV, int n_tiles, int tiles_per_batch) {
    __shared__ bf16x8 wlds[NFRAG * 64];   // 28 KB

    const int tid  = threadIdx.x;
    const int lane = tid & 63;
    const int wid  = blockIdx.x * (blockDim.x >> 6) + (tid >> 6);

    const int lr = lane & 15;   // A-row within tile / D-col within n-tile
    const int lg = lane >> 4;   // k-group
    const int kl = lg * 8;

    const int tile0 = wid * TPW;

    // Stage W into LDS once per block.
    {
        const bf16x8* wsrc = reinterpret_cast<const bf16x8*>(wf);
        for (int i = tid; i < NFRAG * 64; i += 1024)
            wlds[i] = wsrc[i];
    }

    float bias_v[4];
#pragma unroll
    for (int nt = 0; nt < 4; ++nt) bias_v[nt] = bias[nt * 16 + lr];

    __syncthreads();

    if (tile0 >= n_tiles) return;

    // Prefetch ids for the first tile.
    int s = __builtin_nontemporal_load(&snd[(long)tile0 * 16 + lr]);
    int r = __builtin_nontemporal_load(&rcv[(long)tile0 * 16 + lr]);

#pragma unroll
    for (int t = 0; t < TPW; ++t) {
        const int tile = tile0 + t;
        if (tile >= n_tiles) break;

        const int  b   = (tile >= tiles_per_batch) ? 1 : 0;
        const long row = (long)tile * 16 + lr;

        // Gathers first (ids ready).
        const __bf16* vbb = vb16 + (long)b * NV * DV_;
        bf16x8 afrag[7];
        afrag[2] = *reinterpret_cast<const bf16x8*>(vbb + (long)s * DV_ + kl);
        afrag[3] = *reinterpret_cast<const bf16x8*>(vbb + (long)s * DV_ + 32 + kl);
        afrag[4] = *reinterpret_cast<const bf16x8*>(vbb + (long)r * DV_ + kl);
        afrag[5] = *reinterpret_cast<const bf16x8*>(vbb + (long)r * DV_ + 32 + kl);

        // Prefetch next tile's ids.
        if (t + 1 < TPW && tile + 1 < n_tiles) {
            s = __builtin_nontemporal_load(&snd[row + 16]);
            r = __builtin_nontemporal_load(&rcv[row + 16]);
        }

        // Streamed fp32 loads: edata (ks=0,1) NT read-once, ctx (ks=6) cached.
        f32x4 f0[3], f1[3];
#pragma unroll
        for (int ks = 0; ks < 2; ++ks) {
            const f32x4* p = reinterpret_cast<const f32x4*>(edata + row * DE_ + ks * 32 + kl);
            f0[ks] = __builtin_nontemporal_load(p);
            f1[ks] = __builtin_nontemporal_load(p + 1);
        }
        {
            const f32x4* p = reinterpret_cast<const f32x4*>(cdata + b * DC_ + kl);
            f0[2] = p[0];
            f1[2] = p[1];
        }
#pragma unroll
        for (int q = 0; q < 3; ++q) {
            int ks = (q < 2) ? q : 6;
            bf16x8 a;
            a[0] = (__bf16)f0[q][0]; a[1] = (__bf16)f0[q][1];
            a[2] = (__bf16)f0[q][2]; a[3] = (__bf16)f0[q][3];
            a[4] = (__bf16)f1[q][0]; a[5] = (__bf16)f1[q][1];
            a[6] = (__bf16)f1[q][2]; a[7] = (__bf16)f1[q][3];
            afrag[ks] = a;
        }

        f32x4 acc[4];
#pragma unroll
        for (int nt = 0; nt < 4; ++nt) acc[nt] = f32x4{0.f, 0.f, 0.f, 0.f};

#pragma unroll
        for (int ks = 0; ks < 7; ++ks) {
#pragma unroll
            for (int nt = 0; nt < 4; ++nt) {
                bf16x8 w = wlds[(ks * 4 + nt) * 64 + lane];
                acc[nt] = __builtin_amdgcn_mfma_f32_16x16x32_bf16(afrag[ks], w, acc[nt], 0, 0, 0);
            }
        }

        // D layout (m89): col = lane&15 (+16*nt), row = (lane>>4)*4 + j
        const long rb = (long)tile * 16;
#pragma unroll
        for (int nt = 0; nt < 4; ++nt) {
#pragma unroll
            for (int j = 0; j < 4; ++j) {
                float v = acc[nt][j] + bias_v[nt];
                out[(rb + lg * 4 + j) * DOUT_ + nt * 16 + lr] = v > 0.f ? v : 0.f;
            }
        }
    }
}

extern "C" void kernel_launch(void* const* d_in, const int* in_sizes, int n_in,
                              void* d_out, int out_size, void* d_ws, size_t ws_size,
                              hipStream_t stream) {
    const float* edata = (const float*)d_in[0];
    const float* vdata = (const float*)d_in[1];
    const float* cdata = (const float*)d_in[2];
    const int*   snd   = (const int*)d_in[3];
    const int*   rcv   = (const int*)d_in[4];
    const float* W     = (const float*)d_in[5];
    const float* bias  = (const float*)d_in[6];
    float* out = (float*)d_out;

    const int Etot = in_sizes[3];              // B*E = 800000
    const int Bb   = in_sizes[2] / DC_;        // 2
    const int E    = Etot / Bb;                // 400000
    const int NV   = in_sizes[1] / (Bb * DV_); // 50000
    const int n_tiles = (Etot + 15) / 16;      // 50000
    const int tiles_per_batch = E / 16;        // 25000
    const int nvdata = in_sizes[1];            // B*NV*64 elements

    __bf16* wf   = (__bf16*)d_ws;                            // 28 KB fragments
    __bf16* vb16 = (__bf16*)((char*)d_ws + NFRAG * 64 * 16); // bf16 vdata

    hipLaunchKernelGGL(prep_w_kernel, dim3(NFRAG), dim3(64), 0, stream, W, wf);
    {
        int n8 = nvdata / 8;
        hipLaunchKernelGGL(prep_v_kernel, dim3((n8 + 255) / 256), dim3(256), 0,
                           stream, vdata, vb16, n8);
    }

    const int tiles_per_block = 16 * TPW;      // 16 waves x TPW tiles
    const int blocks = (n_tiles + tiles_per_block - 1) / tiles_per_block;
    hipLaunchKernelGGL(edge_mlp_kernel, dim3(blocks), dim3(1024), 0, stream,
                       edata, vb16, cdata, snd, rcv, wf, bias, out,
                       NV, n_tiles, tiles_per_batch);
}

// Round 10
// 115.520 us; speedup vs baseline: 1.2772x; 1.2772x over previous
//
#include <hip/hip_runtime.h>
#include <hip/hip_bf16.h>

typedef __bf16 bf16x8 __attribute__((ext_vector_type(8)));
typedef float  f32x4  __attribute__((ext_vector_type(4)));

#define DE_   64
#define DV_   64
#define DC_   32
#define DOUT_ 64
#define DIN_  224
#define NFRAG 28   // 7 k-steps * 4 n-tiles

// Merged prep: blocks [0, NFRAG) swizzle W into MFMA B-fragment order;
// blocks [NFRAG, ...) convert vdata fp32 -> bf16 (halves gather traffic).
// W layout: frag f = ks*4+nt ; lane holds B[k][col], col = nt*16+(lane&15),
// k = ks*32 + (lane>>4)*8 + j, j=0..7 contiguous -> 16B per lane.
__global__ void prep_kernel(const float* __restrict__ W, __bf16* __restrict__ wf,
                            const float* __restrict__ vdata,
                            __bf16* __restrict__ vb16, int n8) {
    if (blockIdx.x < NFRAG) {
        int f    = blockIdx.x;
        int lane = threadIdx.x;
        if (lane >= 64) return;
        int ks = f >> 2, nt = f & 3;
        int col = nt * 16 + (lane & 15);
        int k0  = ks * 32 + (lane >> 4) * 8;
        bf16x8 v;
#pragma unroll
        for (int j = 0; j < 8; ++j)
            v[j] = (__bf16)W[(k0 + j) * DOUT_ + col];
        reinterpret_cast<bf16x8*>(wf)[f * 64 + lane] = v;
        return;
    }
    int i = (blockIdx.x - NFRAG) * blockDim.x + threadIdx.x;
    if (i >= n8) return;
    f32x4 a = reinterpret_cast<const f32x4*>(vdata)[2 * i];
    f32x4 b = reinterpret_cast<const f32x4*>(vdata)[2 * i + 1];
    bf16x8 v;
    v[0] = (__bf16)a[0]; v[1] = (__bf16)a[1]; v[2] = (__bf16)a[2]; v[3] = (__bf16)a[3];
    v[4] = (__bf16)b[0]; v[5] = (__bf16)b[1]; v[6] = (__bf16)b[2]; v[7] = (__bf16)b[3];
    reinterpret_cast<bf16x8*>(vb16)[i] = v;
}

// One wave per 16-edge tile (R8 structure — empirical optimum).
// 1024-thread blocks (16 waves): 28 KB LDS W-copy amortized over 16 waves,
// 2 blocks/CU = 32 waves/CU. Dense dispatch keeps the live edata/out window
// compact (persistent/TPW variants regressed via cache spreading, R6/R9).
// Single-use streams (edata, ids) nontemporal.
__global__ __launch_bounds__(1024, 2)
void edge_mlp_kernel(const float* __restrict__ edata,
                     const __bf16* __restrict__ vb16,
                     const float* __restrict__ cdata,
                     const int*   __restrict__ snd,
                     const int*   __restrict__ rcv,
                     const __bf16* __restrict__ wf,
                     const float* __restrict__ bias,
                     float* __restrict__ out,
                     int NV, int n_tiles, int tiles_per_batch) {
    __shared__ bf16x8 wlds[NFRAG * 64];   // 28 KB

    const int tid  = threadIdx.x;
    const int lane = tid & 63;
    const int tile = blockIdx.x * (blockDim.x >> 6) + (tid >> 6);
    const bool active = tile < n_tiles;

    const int lr = lane & 15;   // A-row within tile / D-col within n-tile
    const int lg = lane >> 4;   // k-group
    const int kl = lg * 8;

    const int  b   = (tile >= tiles_per_batch) ? 1 : 0;
    const long row = active ? ((long)tile * 16 + lr) : 0;

    // Kick off the dependent chain immediately (NT: ids are read-once).
    const int s = __builtin_nontemporal_load(&snd[row]);
    const int r = __builtin_nontemporal_load(&rcv[row]);

    // Independent loads: edata (ks=0,1) NT read-once stream, ctx (ks=6) cached.
    f32x4 f0[3], f1[3];
#pragma unroll
    for (int ks = 0; ks < 2; ++ks) {
        const f32x4* p = reinterpret_cast<const f32x4*>(edata + row * DE_ + ks * 32 + kl);
        f0[ks] = __builtin_nontemporal_load(p);
        f1[ks] = __builtin_nontemporal_load(p + 1);
    }
    {
        const f32x4* p = reinterpret_cast<const f32x4*>(cdata + b * DC_ + kl);
        f0[2] = p[0];
        f1[2] = p[1];
    }
    float bias_v[4];
#pragma unroll
    for (int nt = 0; nt < 4; ++nt) bias_v[nt] = bias[nt * 16 + lr];

    // Stage W into LDS (hides id-load latency under this + the barrier).
    {
        const bf16x8* wsrc = reinterpret_cast<const bf16x8*>(wf);
        for (int i = tid; i < NFRAG * 64; i += 1024)
            wlds[i] = wsrc[i];
    }
    __syncthreads();

    // Gathered loads, already bf16: one 16B load per lane per k-step.
    const __bf16* vbb = vb16 + (long)b * NV * DV_;
    bf16x8 afrag[7];
#pragma unroll
    for (int ks = 2; ks < 6; ++ks) {
        const __bf16* p = (ks < 4) ? (vbb + (long)s * DV_ + (ks - 2) * 32 + kl)
                                   : (vbb + (long)r * DV_ + (ks - 4) * 32 + kl);
        afrag[ks] = *reinterpret_cast<const bf16x8*>(p);
    }
    // Convert the fp32 streams.
#pragma unroll
    for (int q = 0; q < 3; ++q) {
        int ks = (q < 2) ? q : 6;
        bf16x8 a;
        a[0] = (__bf16)f0[q][0]; a[1] = (__bf16)f0[q][1];
        a[2] = (__bf16)f0[q][2]; a[3] = (__bf16)f0[q][3];
        a[4] = (__bf16)f1[q][0]; a[5] = (__bf16)f1[q][1];
        a[6] = (__bf16)f1[q][2]; a[7] = (__bf16)f1[q][3];
        afrag[ks] = a;
    }

    f32x4 acc[4];
#pragma unroll
    for (int nt = 0; nt < 4; ++nt) acc[nt] = f32x4{0.f, 0.f, 0.f, 0.f};

#pragma unroll
    for (int ks = 0; ks < 7; ++ks) {
#pragma unroll
        for (int nt = 0; nt < 4; ++nt) {
            bf16x8 w = wlds[(ks * 4 + nt) * 64 + lane];
            acc[nt] = __builtin_amdgcn_mfma_f32_16x16x32_bf16(afrag[ks], w, acc[nt], 0, 0, 0);
        }
    }

    if (!active) return;

    // D layout (m89): col = lane&15 (+16*nt), row = (lane>>4)*4 + j
    const long rb = (long)tile * 16;
#pragma unroll
    for (int nt = 0; nt < 4; ++nt) {
#pragma unroll
        for (int j = 0; j < 4; ++j) {
            float v = acc[nt][j] + bias_v[nt];
            out[(rb + lg * 4 + j) * DOUT_ + nt * 16 + lr] = v > 0.f ? v : 0.f;
        }
    }
}

extern "C" void kernel_launch(void* const* d_in, const int* in_sizes, int n_in,
                              void* d_out, int out_size, void* d_ws, size_t ws_size,
                              hipStream_t stream) {
    const float* edata = (const float*)d_in[0];
    const float* vdata = (const float*)d_in[1];
    const float* cdata = (const float*)d_in[2];
    const int*   snd   = (const int*)d_in[3];
    const int*   rcv   = (const int*)d_in[4];
    const float* W     = (const float*)d_in[5];
    const float* bias  = (const float*)d_in[6];
    float* out = (float*)d_out;

    const int Etot = in_sizes[3];              // B*E = 800000
    const int Bb   = in_sizes[2] / DC_;        // 2
    const int E    = Etot / Bb;                // 400000
    const int NV   = in_sizes[1] / (Bb * DV_); // 50000
    const int n_tiles = (Etot + 15) / 16;      // 50000
    const int tiles_per_batch = E / 16;        // 25000
    const int nvdata = in_sizes[1];            // B*NV*64 elements

    __bf16* wf   = (__bf16*)d_ws;                            // 28 KB fragments
    __bf16* vb16 = (__bf16*)((char*)d_ws + NFRAG * 64 * 16); // bf16 vdata

    {
        int n8 = nvdata / 8;
        int vblocks = (n8 + 255) / 256;
        hipLaunchKernelGGL(prep_kernel, dim3(NFRAG + vblocks), dim3(256), 0,
                           stream, W, wf, vdata, vb16, n8);
    }

    const int waves_per_block = 16;            // 1024 threads
    const int blocks = (n_tiles + waves_per_block - 1) / waves_per_block;
    hipLaunchKernelGGL(edge_mlp_kernel, dim3(blocks), dim3(1024), 0, stream,
                       edata, vb16, cdata, snd, rcv, wf, bias, out,
                       NV, n_tiles, tiles_per_batch);
}